// Round 4
// baseline (308.692 us; speedup 1.0000x reference)
//
#include <hip/hip_runtime.h>
#include <hip/hip_cooperative_groups.h>
#include <math.h>

namespace cg = cooperative_groups;

// B=16, C=256, deeper 32x32, shallower 64x64 (fixed by reference).
// ws layout (floats): gp[16*512] | h[16*256] | sig[16*256]  (64 KB)

// ---------------- fused cooperative kernel (small LDS: ~5.7 KB) ----------------
__global__ __launch_bounds__(256, 4) void fused_kernel(
    const float* __restrict__ deeper, const float* __restrict__ shallower,
    const float* __restrict__ w1, const float* __restrict__ b1,
    const float* __restrict__ w2, const float* __restrict__ b2,
    float* __restrict__ out, float* __restrict__ gp, float* __restrict__ h,
    float* __restrict__ sig)
{
    cg::grid_group grid = cg::this_grid();
    const int t = threadIdx.x;
    const int nblk = gridDim.x;

    __shared__ float red_sh[4], red_dp[4];
    __shared__ float part[256];
    __shared__ float tile[32 * 36];

    // ---- Phase 1: global average pools ----
    for (int bc = blockIdx.x; bc < 4096; bc += nblk) {
        __syncthreads();   // protect red_* reuse across iterations
        const float4* ssrc = (const float4*)(shallower + (size_t)bc * 4096);
        const float4* dsrc = (const float4*)(deeper + (size_t)bc * 1024);
        float4 a = ssrc[t];
        float4 b = ssrc[t + 256];
        float4 c = ssrc[t + 512];
        float4 d = ssrc[t + 768];
        float4 e = dsrc[t];
        float s_sh = (a.x + a.y + a.z + a.w) + (b.x + b.y + b.z + b.w)
                   + (c.x + c.y + c.z + c.w) + (d.x + d.y + d.z + d.w);
        float s_dp = e.x + e.y + e.z + e.w;
        #pragma unroll
        for (int off = 32; off > 0; off >>= 1) {
            s_sh += __shfl_down(s_sh, off, 64);
            s_dp += __shfl_down(s_dp, off, 64);
        }
        if ((t & 63) == 0) { red_sh[t >> 6] = s_sh; red_dp[t >> 6] = s_dp; }
        __syncthreads();
        if (t == 0) {
            const int bb = bc >> 8, cc = bc & 255;
            gp[bb * 512 + cc]       = (red_sh[0] + red_sh[1] + red_sh[2] + red_sh[3]) * (1.0f / 4096.0f);
            gp[bb * 512 + 256 + cc] = (red_dp[0] + red_dp[1] + red_dp[2] + red_dp[3]) * (1.0f / 1024.0f);
        }
    }
    grid.sync();

    // ---- Phase 2a: h[b,j] = relu(gp[b,:512] . w1[j,:512] + b1[j]) ----
    // block j handles output column j for all 16 b; thread = (b, kchunk)
    for (int j = blockIdx.x; j < 256; j += nblk) {
        __syncthreads();
        const int b = t >> 4, kc = t & 15;
        const float4* gv = (const float4*)(gp + b * 512 + kc * 32);
        const float4* wv = (const float4*)(w1 + (size_t)j * 512 + kc * 32);
        float acc = 0.0f;
        #pragma unroll
        for (int i = 0; i < 8; ++i) {
            float4 g = gv[i], w = wv[i];
            acc += g.x * w.x + g.y * w.y + g.z * w.z + g.w * w.w;
        }
        part[t] = acc;
        __syncthreads();
        if (t < 16) {
            float v = 0.0f;
            #pragma unroll
            for (int k = 0; k < 16; ++k) v += part[t * 16 + k];
            h[t * 256 + j] = fmaxf(v + b1[j], 0.0f);
        }
    }
    grid.sync();

    // ---- Phase 2b: sig[b,j] = sigmoid(h[b,:256] . w2[j,:256] + b2[j]) ----
    for (int j = blockIdx.x; j < 256; j += nblk) {
        __syncthreads();
        const int b = t >> 4, kc = t & 15;
        const float4* hv = (const float4*)(h + b * 256 + kc * 16);
        const float4* wv = (const float4*)(w2 + (size_t)j * 256 + kc * 16);
        float acc = 0.0f;
        #pragma unroll
        for (int i = 0; i < 4; ++i) {
            float4 g = hv[i], w = wv[i];
            acc += g.x * w.x + g.y * w.y + g.z * w.z + g.w * w.w;
        }
        part[t] = acc;
        __syncthreads();
        if (t < 16) {
            float v = 0.0f;
            #pragma unroll
            for (int k = 0; k < 16; ++k) v += part[t * 16 + k];
            sig[t * 256 + j] = 1.0f / (1.0f + expf(-(v + b2[j])));
        }
    }
    grid.sync();

    // ---- Phase 3: out = shallower*sig + bilinear2x(deeper) ----
    for (int bc = blockIdx.x; bc < 4096; bc += nblk) {
        __syncthreads();   // protect tile reuse across iterations
        {
            float4 v = ((const float4*)(deeper + (size_t)bc * 1024))[t];  // L3-warm
            const int row = t >> 3, col4 = t & 7;
            *(float4*)(&tile[row * 36 + col4 * 4]) = v;
        }
        const float sv = sig[bc];
        __syncthreads();
        const float4* ssrc = (const float4*)(shallower + (size_t)bc * 4096);
        float4* dst = (float4*)(out + (size_t)bc * 4096);
        #pragma unroll
        for (int j = 0; j < 4; ++j) {
            const int f4 = t + j * 256;
            const int y = f4 >> 4;
            const int m = f4 & 15;
            const int yy = 2 * y - 1;
            const int yl = yy >> 2;
            const float wy = (float)(yy & 3) * 0.25f;
            const float wy1 = 1.0f - wy;
            const int y0 = yl < 0 ? 0 : yl;
            const int y1 = (yl + 1) > 31 ? 31 : (yl + 1);
            const float* r0 = &tile[y0 * 36];
            const float* r1 = &tile[y1 * 36];
            const int xa = (2 * m - 1) < 0 ? 0 : (2 * m - 1);
            const int xd = (2 * m + 2) > 31 ? 31 : (2 * m + 2);
            const float A  = r0[xa]        * wy1 + r1[xa]        * wy;
            const float Bv = r0[2 * m]     * wy1 + r1[2 * m]     * wy;
            const float Cv = r0[2 * m + 1] * wy1 + r1[2 * m + 1] * wy;
            const float D  = r0[xd]        * wy1 + r1[xd]        * wy;
            float4 sh = ssrc[f4];
            float4 o;
            o.x = fmaf(sh.x, sv, 0.25f * A  + 0.75f * Bv);
            o.y = fmaf(sh.y, sv, 0.75f * Bv + 0.25f * Cv);
            o.z = fmaf(sh.z, sv, 0.25f * Bv + 0.75f * Cv);
            o.w = fmaf(sh.w, sv, 0.75f * Cv + 0.25f * D);
            dst[f4] = o;
        }
    }
}

// ---------------- proven fallback path (R2 kernels) ----------------
__global__ __launch_bounds__(256) void pool_kernel(const float* __restrict__ deeper,
                                                   const float* __restrict__ shallower,
                                                   float* __restrict__ gp) {
    const int bc = blockIdx.x;
    const int t = threadIdx.x;
    const float4* ssrc = (const float4*)(shallower + (size_t)bc * 4096);
    const float4* dsrc = (const float4*)(deeper + (size_t)bc * 1024);
    float4 a = ssrc[t], b = ssrc[t + 256], c = ssrc[t + 512], d = ssrc[t + 768];
    float4 e = dsrc[t];
    float s_sh = (a.x + a.y + a.z + a.w) + (b.x + b.y + b.z + b.w)
               + (c.x + c.y + c.z + c.w) + (d.x + d.y + d.z + d.w);
    float s_dp = e.x + e.y + e.z + e.w;
    #pragma unroll
    for (int off = 32; off > 0; off >>= 1) {
        s_sh += __shfl_down(s_sh, off, 64);
        s_dp += __shfl_down(s_dp, off, 64);
    }
    __shared__ float red_sh[4], red_dp[4];
    if ((t & 63) == 0) { red_sh[t >> 6] = s_sh; red_dp[t >> 6] = s_dp; }
    __syncthreads();
    if (t == 0) {
        int bb = bc >> 8, cc = bc & 255;
        gp[bb * 512 + cc]       = (red_sh[0]+red_sh[1]+red_sh[2]+red_sh[3]) * (1.0f / 4096.0f);
        gp[bb * 512 + 256 + cc] = (red_dp[0]+red_dp[1]+red_dp[2]+red_dp[3]) * (1.0f / 1024.0f);
    }
}

__global__ __launch_bounds__(256) void mlp1_kernel(const float* __restrict__ gp,
                                                   const float* __restrict__ w1,
                                                   const float* __restrict__ b1,
                                                   float* __restrict__ h) {
    const int j = blockIdx.x;
    const int t = threadIdx.x;
    const int half = t >> 7;
    const int b = (t >> 3) & 15;
    const int o = j * 8 + (t & 7);
    const float4* gv = (const float4*)(gp + b * 512 + half * 256);
    const float4* wv = (const float4*)(w1 + (size_t)o * 512 + half * 256);
    float acc = 0.0f;
    #pragma unroll 8
    for (int i = 0; i < 64; ++i) {
        float4 g = gv[i], w = wv[i];
        acc += g.x * w.x + g.y * w.y + g.z * w.z + g.w * w.w;
    }
    __shared__ float part[256];
    part[t] = acc;
    __syncthreads();
    if (t < 128) h[b * 256 + o] = fmaxf(part[t] + part[t + 128] + b1[o], 0.0f);
}

__global__ __launch_bounds__(256) void mlp2_kernel(const float* __restrict__ h,
                                                   const float* __restrict__ w2,
                                                   const float* __restrict__ b2,
                                                   float* __restrict__ sig) {
    const int j = blockIdx.x;
    const int t = threadIdx.x;
    const int half = t >> 7;
    const int b = (t >> 3) & 15;
    const int o = j * 8 + (t & 7);
    const float4* hv = (const float4*)(h + b * 256 + half * 128);
    const float4* wv = (const float4*)(w2 + (size_t)o * 256 + half * 128);
    float acc = 0.0f;
    #pragma unroll 8
    for (int i = 0; i < 32; ++i) {
        float4 g = hv[i], w = wv[i];
        acc += g.x * w.x + g.y * w.y + g.z * w.z + g.w * w.w;
    }
    __shared__ float part[256];
    part[t] = acc;
    __syncthreads();
    if (t < 128) sig[b * 256 + o] = 1.0f / (1.0f + expf(-(part[t] + part[t + 128] + b2[o])));
}

__global__ __launch_bounds__(256) void out_kernel(const float* __restrict__ deeper,
                                                  const float* __restrict__ shallower,
                                                  const float* __restrict__ sig,
                                                  float* __restrict__ out) {
    const int bc = blockIdx.x;
    const int t = threadIdx.x;
    __shared__ float tile[32 * 36];
    {
        float4 v = ((const float4*)(deeper + (size_t)bc * 1024))[t];
        int row = t >> 3, col4 = t & 7;
        *(float4*)(tile + row * 36 + col4 * 4) = v;
    }
    const float s = sig[bc];
    __syncthreads();
    const float4* ssrc = (const float4*)(shallower + (size_t)bc * 4096);
    float4* dst = (float4*)(out + (size_t)bc * 4096);
    #pragma unroll
    for (int j = 0; j < 4; ++j) {
        const int f4 = t + j * 256;
        const int y = f4 >> 4;
        const int m = f4 & 15;
        const int yy = 2 * y - 1;
        const int yl = yy >> 2;
        const float wy = (float)(yy & 3) * 0.25f;
        const float wy1 = 1.0f - wy;
        const int y0 = yl < 0 ? 0 : yl;
        const int y1 = (yl + 1) > 31 ? 31 : (yl + 1);
        const float* r0 = tile + y0 * 36;
        const float* r1 = tile + y1 * 36;
        const int xa = (2 * m - 1) < 0 ? 0 : (2 * m - 1);
        const int xd = (2 * m + 2) > 31 ? 31 : (2 * m + 2);
        const float A  = r0[xa]        * wy1 + r1[xa]        * wy;
        const float Bv = r0[2 * m]     * wy1 + r1[2 * m]     * wy;
        const float Cv = r0[2 * m + 1] * wy1 + r1[2 * m + 1] * wy;
        const float D  = r0[xd]        * wy1 + r1[xd]        * wy;
        float4 sh = ssrc[f4];
        float4 o;
        o.x = fmaf(sh.x, s, 0.25f * A  + 0.75f * Bv);
        o.y = fmaf(sh.y, s, 0.75f * Bv + 0.25f * Cv);
        o.z = fmaf(sh.z, s, 0.25f * Bv + 0.75f * Cv);
        o.w = fmaf(sh.w, s, 0.75f * Cv + 0.25f * D);
        dst[f4] = o;
    }
}

extern "C" void kernel_launch(void* const* d_in, const int* in_sizes, int n_in,
                              void* d_out, int out_size, void* d_ws, size_t ws_size,
                              hipStream_t stream) {
    const float* deeper    = (const float*)d_in[0];
    const float* shallower = (const float*)d_in[1];
    const float* w1        = (const float*)d_in[2];
    const float* b1        = (const float*)d_in[3];
    const float* w2        = (const float*)d_in[4];
    const float* b2        = (const float*)d_in[5];
    float* outp = (float*)d_out;

    float* gp = (float*)d_ws;         // 16*512
    float* h  = gp + 16 * 512;        // 16*256
    float* sg = h + 16 * 256;         // 16*256

    // Size the cooperative grid from the occupancy query (pure query: capture-safe,
    // deterministic -> correctness call and captured call take the same branch).
    int bpc = 0;
    hipError_t qerr = hipOccupancyMaxActiveBlocksPerMultiprocessor(&bpc, fused_kernel, 256, 0);
    bool coop = (qerr == hipSuccess) && (bpc >= 1);
    if (coop) {
        int grid = bpc * 256;             // 256 CUs on MI355X
        if (grid > 4096) grid = 4096;
        void* args[] = { (void*)&deeper, (void*)&shallower, (void*)&w1, (void*)&b1,
                         (void*)&w2, (void*)&b2, (void*)&outp, (void*)&gp, (void*)&h,
                         (void*)&sg };
        hipError_t lerr = hipLaunchCooperativeKernel((const void*)fused_kernel,
                                                     dim3(grid), dim3(256), args, 0, stream);
        if (lerr != hipSuccess) { (void)hipGetLastError(); coop = false; }
    }
    if (!coop) {
        hipLaunchKernelGGL(pool_kernel, dim3(4096), dim3(256), 0, stream, deeper, shallower, gp);
        hipLaunchKernelGGL(mlp1_kernel, dim3(32), dim3(256), 0, stream, gp, w1, b1, h);
        hipLaunchKernelGGL(mlp2_kernel, dim3(32), dim3(256), 0, stream, h, w2, b2, sg);
        hipLaunchKernelGGL(out_kernel, dim3(4096), dim3(256), 0, stream, deeper, shallower, sg, outp);
    }
}

// Round 5
// 257.195 us; speedup vs baseline: 1.2002x; 1.2002x over previous
//
#include <hip/hip_runtime.h>
#include <math.h>

// B=16, C=256, deeper 32x32, shallower 64x64 (fixed by reference).
// ws layout (floats): gp[8192] | h[4096] | sig[4096] | cnt[17] (u32)
// Two dispatches: pool+MLP (ticket-barrier tail) then gating+upsample.

#define NPOOL 4096
#define NSPIN 64   // last 64 tickets: block k -> batch=k>>2, output-quarter=k&3

__global__ __launch_bounds__(256) void pool_mlp_kernel(
    const float* __restrict__ deeper, const float* __restrict__ shallower,
    const float* __restrict__ w1, const float* __restrict__ b1,
    const float* __restrict__ w2, const float* __restrict__ b2,
    float* __restrict__ gp, float* __restrict__ h, float* __restrict__ sig,
    unsigned int* __restrict__ cnt)   // cnt[0]=global ticket, cnt[1+b]=per-batch
{
    const int bc = blockIdx.x;        // 0..4095 = b*256 + c
    const int t = threadIdx.x;
    __shared__ float red_sh[4], red_dp[4];
    __shared__ float buf[512];        // gp[b] then h[b] staging
    __shared__ float part[256];
    __shared__ unsigned int ticket_s;

    // ---------- Phase A: pool (identical math to R2) ----------
    {
        const float4* ssrc = (const float4*)(shallower + (size_t)bc * 4096);
        const float4* dsrc = (const float4*)(deeper + (size_t)bc * 1024);
        float4 a = ssrc[t], b4 = ssrc[t + 256], c4 = ssrc[t + 512], d4 = ssrc[t + 768];
        float4 e = dsrc[t];
        float s_sh = (a.x + a.y + a.z + a.w) + (b4.x + b4.y + b4.z + b4.w)
                   + (c4.x + c4.y + c4.z + c4.w) + (d4.x + d4.y + d4.z + d4.w);
        float s_dp = e.x + e.y + e.z + e.w;
        #pragma unroll
        for (int off = 32; off > 0; off >>= 1) {
            s_sh += __shfl_down(s_sh, off, 64);
            s_dp += __shfl_down(s_dp, off, 64);
        }
        if ((t & 63) == 0) { red_sh[t >> 6] = s_sh; red_dp[t >> 6] = s_dp; }
        __syncthreads();
        if (t == 0) {
            const int bb = bc >> 8, cc = bc & 255;
            const float vsh = (red_sh[0] + red_sh[1] + red_sh[2] + red_sh[3]) * (1.0f / 4096.0f);
            const float vdp = (red_dp[0] + red_dp[1] + red_dp[2] + red_dp[3]) * (1.0f / 1024.0f);
            __hip_atomic_store(&gp[bb * 512 + cc], vsh,
                               __ATOMIC_RELAXED, __HIP_MEMORY_SCOPE_AGENT);
            __hip_atomic_store(&gp[bb * 512 + 256 + cc], vdp,
                               __ATOMIC_RELAXED, __HIP_MEMORY_SCOPE_AGENT);
            __threadfence();
            ticket_s = __hip_atomic_fetch_add(&cnt[0], 1u,
                                              __ATOMIC_RELEASE, __HIP_MEMORY_SCOPE_AGENT);
        }
        __syncthreads();
    }
    const unsigned int ticket = ticket_s;
    if (ticket < NPOOL - NSPIN) return;          // pool-only blocks exit

    // ---------- Phase B: MLP on the last 64 finisher blocks ----------
    const int k = (int)ticket - (NPOOL - NSPIN); // 0..63
    const int b = k >> 2, q = k & 3;

    if (t == 0) {  // wait until every block's gp stores are released
        while (__hip_atomic_load(&cnt[0], __ATOMIC_ACQUIRE, __HIP_MEMORY_SCOPE_AGENT) < NPOOL)
            __builtin_amdgcn_s_sleep(8);
    }
    __syncthreads();

    buf[t]       = __hip_atomic_load(&gp[b * 512 + t],       __ATOMIC_RELAXED, __HIP_MEMORY_SCOPE_AGENT);
    buf[t + 256] = __hip_atomic_load(&gp[b * 512 + 256 + t], __ATOMIC_RELAXED, __HIP_MEMORY_SCOPE_AGENT);
    __syncthreads();

    // layer1: outputs o = q*64 + (t>>2); thread covers k-chunk (t&3)*128
    {
        const int ol = t >> 2, kc = t & 3;
        const int o = q * 64 + ol;
        const float4* wv = (const float4*)(w1 + (size_t)o * 512 + kc * 128);
        const float4* gv = (const float4*)(buf + kc * 128);
        float acc = 0.0f;
        #pragma unroll
        for (int i = 0; i < 32; ++i) {
            float4 w = wv[i], g = gv[i];
            acc += g.x * w.x + g.y * w.y + g.z * w.z + g.w * w.w;
        }
        part[t] = acc;
    }
    __syncthreads();
    if (t < 64) {
        const int o = q * 64 + t;
        const float v = part[t * 4] + part[t * 4 + 1] + part[t * 4 + 2] + part[t * 4 + 3] + b1[o];
        __hip_atomic_store(&h[b * 256 + o], fmaxf(v, 0.0f),
                           __ATOMIC_RELAXED, __HIP_MEMORY_SCOPE_AGENT);
    }
    __syncthreads();
    if (t == 0) {   // per-batch 4-block barrier
        __threadfence();
        __hip_atomic_fetch_add(&cnt[1 + b], 1u, __ATOMIC_RELEASE, __HIP_MEMORY_SCOPE_AGENT);
        while (__hip_atomic_load(&cnt[1 + b], __ATOMIC_ACQUIRE, __HIP_MEMORY_SCOPE_AGENT) < 4u)
            __builtin_amdgcn_s_sleep(8);
    }
    __syncthreads();
    buf[t] = __hip_atomic_load(&h[b * 256 + t], __ATOMIC_RELAXED, __HIP_MEMORY_SCOPE_AGENT);
    __syncthreads();

    // layer2: sig[b, q*64 + t>>2]
    {
        const int ol = t >> 2, kc = t & 3;
        const int o = q * 64 + ol;
        const float4* wv = (const float4*)(w2 + (size_t)o * 256 + kc * 64);
        const float4* hv = (const float4*)(buf + kc * 64);
        float acc = 0.0f;
        #pragma unroll
        for (int i = 0; i < 16; ++i) {
            float4 w = wv[i], g = hv[i];
            acc += g.x * w.x + g.y * w.y + g.z * w.z + g.w * w.w;
        }
        part[t] = acc;
    }
    __syncthreads();
    if (t < 64) {
        const int o = q * 64 + t;
        const float v = part[t * 4] + part[t * 4 + 1] + part[t * 4 + 2] + part[t * 4 + 3] + b2[o];
        sig[b * 256 + o] = 1.0f / (1.0f + expf(-v));   // plain store: next dispatch reads
    }
}

// ---------- out = shallower*sig + bilinear2x(deeper) (proven R2 kernel) ----------
__global__ __launch_bounds__(256) void out_kernel(const float* __restrict__ deeper,
                                                  const float* __restrict__ shallower,
                                                  const float* __restrict__ sig,
                                                  float* __restrict__ out) {
    const int bc = blockIdx.x;
    const int t = threadIdx.x;
    __shared__ float tile[32 * 36];
    {
        float4 v = ((const float4*)(deeper + (size_t)bc * 1024))[t];
        int row = t >> 3, col4 = t & 7;
        *(float4*)(tile + row * 36 + col4 * 4) = v;
    }
    const float s = sig[bc];
    __syncthreads();
    const float4* ssrc = (const float4*)(shallower + (size_t)bc * 4096);
    float4* dst = (float4*)(out + (size_t)bc * 4096);
    #pragma unroll
    for (int j = 0; j < 4; ++j) {
        const int f4 = t + j * 256;
        const int y = f4 >> 4;
        const int m = f4 & 15;
        const int yy = 2 * y - 1;
        const int yl = yy >> 2;
        const float wy = (float)(yy & 3) * 0.25f;
        const float wy1 = 1.0f - wy;
        const int y0 = yl < 0 ? 0 : yl;
        const int y1 = (yl + 1) > 31 ? 31 : (yl + 1);
        const float* r0 = tile + y0 * 36;
        const float* r1 = tile + y1 * 36;
        const int xa = (2 * m - 1) < 0 ? 0 : (2 * m - 1);
        const int xd = (2 * m + 2) > 31 ? 31 : (2 * m + 2);
        const float A  = r0[xa]        * wy1 + r1[xa]        * wy;
        const float Bv = r0[2 * m]     * wy1 + r1[2 * m]     * wy;
        const float Cv = r0[2 * m + 1] * wy1 + r1[2 * m + 1] * wy;
        const float D  = r0[xd]        * wy1 + r1[xd]        * wy;
        float4 sh = ssrc[f4];
        float4 o;
        o.x = fmaf(sh.x, s, 0.25f * A  + 0.75f * Bv);
        o.y = fmaf(sh.y, s, 0.75f * Bv + 0.25f * Cv);
        o.z = fmaf(sh.z, s, 0.25f * Bv + 0.75f * Cv);
        o.w = fmaf(sh.w, s, 0.75f * Cv + 0.25f * D);
        dst[f4] = o;
    }
}

extern "C" void kernel_launch(void* const* d_in, const int* in_sizes, int n_in,
                              void* d_out, int out_size, void* d_ws, size_t ws_size,
                              hipStream_t stream) {
    const float* deeper    = (const float*)d_in[0];  // [16,256,32,32]
    const float* shallower = (const float*)d_in[1];  // [16,256,64,64]
    const float* w1        = (const float*)d_in[2];  // [256,512]
    const float* b1        = (const float*)d_in[3];  // [256]
    const float* w2        = (const float*)d_in[4];  // [256,256]
    const float* b2        = (const float*)d_in[5];  // [256]
    float* outp = (float*)d_out;

    float* gp = (float*)d_ws;              // 8192 floats
    float* h  = gp + 8192;                 // 4096 floats
    float* sg = h + 4096;                  // 4096 floats
    unsigned int* cnt = (unsigned int*)(sg + 4096);   // 17 u32

    hipMemsetAsync(cnt, 0, 17 * sizeof(unsigned int), stream);
    hipLaunchKernelGGL(pool_mlp_kernel, dim3(NPOOL), dim3(256), 0, stream,
                       deeper, shallower, w1, b1, w2, b2, gp, h, sg, cnt);
    hipLaunchKernelGGL(out_kernel, dim3(4096), dim3(256), 0, stream,
                       deeper, shallower, sg, outp);
}

// Round 6
// 63.981 us; speedup vs baseline: 4.8247x; 4.0199x over previous
//
#include <hip/hip_runtime.h>
#include <math.h>

// B=16, C=256, deeper 32x32, shallower 64x64 (fixed by reference).
// ws layout (floats): gp[16*512] | sig[16*256]
// 3 dispatches: pool -> fused MLP -> gate+upsample. Dispatch boundaries are the
// global barriers (R4/R5 proved grid.sync / ticket barriers cost 100x more).

// ---------- 1) pool: one block per (b,c); means of both inputs ----------
__global__ __launch_bounds__(256) void pool_kernel(const float* __restrict__ deeper,
                                                   const float* __restrict__ shallower,
                                                   float* __restrict__ gp) {
    const int bc = blockIdx.x;   // b*256 + c
    const int t = threadIdx.x;
    const float4* ssrc = (const float4*)(shallower + (size_t)bc * 4096);
    const float4* dsrc = (const float4*)(deeper + (size_t)bc * 1024);
    float4 a = ssrc[t], b4 = ssrc[t + 256], c4 = ssrc[t + 512], d4 = ssrc[t + 768];
    float4 e = dsrc[t];
    float s_sh = (a.x + a.y + a.z + a.w) + (b4.x + b4.y + b4.z + b4.w)
               + (c4.x + c4.y + c4.z + c4.w) + (d4.x + d4.y + d4.z + d4.w);
    float s_dp = e.x + e.y + e.z + e.w;
    #pragma unroll
    for (int off = 32; off > 0; off >>= 1) {
        s_sh += __shfl_down(s_sh, off, 64);
        s_dp += __shfl_down(s_dp, off, 64);
    }
    __shared__ float red_sh[4], red_dp[4];
    if ((t & 63) == 0) { red_sh[t >> 6] = s_sh; red_dp[t >> 6] = s_dp; }
    __syncthreads();
    if (t == 0) {
        const int bb = bc >> 8, cc = bc & 255;
        gp[bb * 512 + cc]       = (red_sh[0]+red_sh[1]+red_sh[2]+red_sh[3]) * (1.0f / 4096.0f);
        gp[bb * 512 + 256 + cc] = (red_dp[0]+red_dp[1]+red_dp[2]+red_dp[3]) * (1.0f / 1024.0f);
    }
}

// ---------- 2) fused MLP: block = batch; both layers, LDS-staged ----------
__global__ __launch_bounds__(256) void mlp_kernel(const float* __restrict__ gp,
                                                  const float* __restrict__ w1,
                                                  const float* __restrict__ b1,
                                                  const float* __restrict__ w2,
                                                  const float* __restrict__ b2,
                                                  float* __restrict__ sig) {
    const int b = blockIdx.x;    // 16
    const int t = threadIdx.x;   // 256 = output index
    __shared__ float buf[512];
    __shared__ float hl[256];
    buf[t]       = gp[b * 512 + t];
    buf[t + 256] = gp[b * 512 + 256 + t];
    __syncthreads();
    {
        const float4* wv = (const float4*)(w1 + (size_t)t * 512);
        const float4* gv = (const float4*)buf;
        float acc = b1[t];
        #pragma unroll 8
        for (int i = 0; i < 128; ++i) {
            float4 g = gv[i], w = wv[i];
            acc += g.x * w.x + g.y * w.y + g.z * w.z + g.w * w.w;
        }
        hl[t] = fmaxf(acc, 0.0f);
    }
    __syncthreads();
    {
        const float4* wv = (const float4*)(w2 + (size_t)t * 256);
        const float4* hv = (const float4*)hl;
        float acc = b2[t];
        #pragma unroll 8
        for (int i = 0; i < 64; ++i) {
            float4 g = hv[i], w = wv[i];
            acc += g.x * w.x + g.y * w.y + g.z * w.z + g.w * w.w;
        }
        sig[b * 256 + t] = 1.0f / (1.0f + expf(-acc));
    }
}

// ---------- 3) out = shallower*sig + bilinear2x(deeper) ----------
// 2x4-output-patch mapping: rowpair r uses input rows {r-1, r, r+1} (clamped),
// col group m uses input cols {2m-1, 2m, 2m+1, 2m+2} (clamped).
// y=2r:   0.25*row[r-1] + 0.75*row[r]
// y=2r+1: 0.75*row[r]   + 0.25*row[r+1]
// x=4m..4m+3: {.25A+.75B, .75B+.25C, .25B+.75C, .75C+.25D}
__global__ __launch_bounds__(256) void out_kernel(const float* __restrict__ deeper,
                                                  const float* __restrict__ shallower,
                                                  const float* __restrict__ sig,
                                                  float* __restrict__ out) {
    const int bc = blockIdx.x;   // 4096
    const int t = threadIdx.x;
    __shared__ float tile[32 * 36];
    {
        float4 v = ((const float4*)(deeper + (size_t)bc * 1024))[t];
        const int row = t >> 3, col4 = t & 7;
        *(float4*)(tile + row * 36 + col4 * 4) = v;
    }
    const float s = sig[bc];
    __syncthreads();
    const float4* ssrc = (const float4*)(shallower + (size_t)bc * 4096);
    float4* dst = (float4*)(out + (size_t)bc * 4096);
    #pragma unroll
    for (int j = 0; j < 2; ++j) {
        const int pi = t + j * 256;          // patch index 0..511
        const int r = pi >> 4;               // rowpair 0..31
        const int m = pi & 15;               // col group 0..15
        const int rm = (r == 0) ? 0 : r - 1;
        const int rp = (r == 31) ? 31 : r + 1;
        const int xa = (m == 0) ? 0 : 2 * m - 1;
        const int xd = (m == 15) ? 31 : 2 * m + 2;
        const float* p0 = tile + rm * 36;
        const float* p1 = tile + r * 36;
        const float* p2 = tile + rp * 36;
        // vertical interpolation of the 4 needed input columns, both output rows
        const float A0 = 0.25f * p0[xa]        + 0.75f * p1[xa];
        const float B0 = 0.25f * p0[2 * m]     + 0.75f * p1[2 * m];
        const float C0 = 0.25f * p0[2 * m + 1] + 0.75f * p1[2 * m + 1];
        const float D0 = 0.25f * p0[xd]        + 0.75f * p1[xd];
        const float A1 = 0.75f * p1[xa]        + 0.25f * p2[xa];
        const float B1 = 0.75f * p1[2 * m]     + 0.25f * p2[2 * m];
        const float C1 = 0.75f * p1[2 * m + 1] + 0.25f * p2[2 * m + 1];
        const float D1 = 0.75f * p1[xd]        + 0.25f * p2[xd];
        const int i0 = 32 * r + m;           // f4 index of output row 2r
        const int i1 = i0 + 16;              // f4 index of output row 2r+1
        float4 sh0 = ssrc[i0];
        float4 sh1 = ssrc[i1];
        float4 o0, o1;
        o0.x = fmaf(sh0.x, s, 0.25f * A0 + 0.75f * B0);
        o0.y = fmaf(sh0.y, s, 0.75f * B0 + 0.25f * C0);
        o0.z = fmaf(sh0.z, s, 0.25f * B0 + 0.75f * C0);
        o0.w = fmaf(sh0.w, s, 0.75f * C0 + 0.25f * D0);
        o1.x = fmaf(sh1.x, s, 0.25f * A1 + 0.75f * B1);
        o1.y = fmaf(sh1.y, s, 0.75f * B1 + 0.25f * C1);
        o1.z = fmaf(sh1.z, s, 0.25f * B1 + 0.75f * C1);
        o1.w = fmaf(sh1.w, s, 0.75f * C1 + 0.25f * D1);
        dst[i0] = o0;
        dst[i1] = o1;
    }
}

extern "C" void kernel_launch(void* const* d_in, const int* in_sizes, int n_in,
                              void* d_out, int out_size, void* d_ws, size_t ws_size,
                              hipStream_t stream) {
    const float* deeper    = (const float*)d_in[0];  // [16,256,32,32]
    const float* shallower = (const float*)d_in[1];  // [16,256,64,64]
    const float* w1        = (const float*)d_in[2];  // [256,512]
    const float* b1        = (const float*)d_in[3];  // [256]
    const float* w2        = (const float*)d_in[4];  // [256,256]
    const float* b2        = (const float*)d_in[5];  // [256]
    float* outp = (float*)d_out;

    float* gp = (float*)d_ws;          // 16*512
    float* sg = gp + 16 * 512;         // 16*256

    hipLaunchKernelGGL(pool_kernel, dim3(4096), dim3(256), 0, stream, deeper, shallower, gp);
    hipLaunchKernelGGL(mlp_kernel, dim3(16), dim3(256), 0, stream, gp, w1, b1, w2, b2, sg);
    hipLaunchKernelGGL(out_kernel, dim3(4096), dim3(256), 0, stream, deeper, shallower, sg, outp);
}

// Round 7
// 51.964 us; speedup vs baseline: 5.9405x; 1.2313x over previous
//
#include <hip/hip_runtime.h>
#include <math.h>

// B=16, C=256, deeper 32x32, shallower 64x64 (fixed by reference).
// ws layout (floats): gp[16*512] | h[16*256]
// 3 dispatches: pool -> mlp layer1 -> out (inline layer2 + gate + upsample).
// R4/R5 proved intra-kernel cross-block sync costs 100x a dispatch boundary;
// R6 proved concentrating weight reads in few blocks costs more than a boundary.

// ---------- 1) pool: one block per (b,c); means of both inputs (R2-proven) ----------
__global__ __launch_bounds__(256) void pool_kernel(const float* __restrict__ deeper,
                                                   const float* __restrict__ shallower,
                                                   float* __restrict__ gp) {
    const int bc = blockIdx.x;   // b*256 + c
    const int t = threadIdx.x;
    const float4* ssrc = (const float4*)(shallower + (size_t)bc * 4096);
    const float4* dsrc = (const float4*)(deeper + (size_t)bc * 1024);
    float4 a = ssrc[t], b4 = ssrc[t + 256], c4 = ssrc[t + 512], d4 = ssrc[t + 768];
    float4 e = dsrc[t];
    float s_sh = (a.x + a.y + a.z + a.w) + (b4.x + b4.y + b4.z + b4.w)
               + (c4.x + c4.y + c4.z + c4.w) + (d4.x + d4.y + d4.z + d4.w);
    float s_dp = e.x + e.y + e.z + e.w;
    #pragma unroll
    for (int off = 32; off > 0; off >>= 1) {
        s_sh += __shfl_down(s_sh, off, 64);
        s_dp += __shfl_down(s_dp, off, 64);
    }
    __shared__ float red_sh[4], red_dp[4];
    if ((t & 63) == 0) { red_sh[t >> 6] = s_sh; red_dp[t >> 6] = s_dp; }
    __syncthreads();
    if (t == 0) {
        const int bb = bc >> 8, cc = bc & 255;
        gp[bb * 512 + cc]       = (red_sh[0]+red_sh[1]+red_sh[2]+red_sh[3]) * (1.0f / 4096.0f);
        gp[bb * 512 + 256 + cc] = (red_dp[0]+red_dp[1]+red_dp[2]+red_dp[3]) * (1.0f / 1024.0f);
    }
}

// ---------- 2) mlp layer1: h[b,o] = relu(gp[b,:512].w1[o,:512] + b1[o]) ----------
// 32 blocks x 256 thr (R2-proven): block j covers o in [8j,8j+8), split-K=2.
__global__ __launch_bounds__(256) void mlp1_kernel(const float* __restrict__ gp,
                                                   const float* __restrict__ w1,
                                                   const float* __restrict__ b1,
                                                   float* __restrict__ h) {
    const int j = blockIdx.x;
    const int t = threadIdx.x;
    const int half = t >> 7;
    const int b = (t >> 3) & 15;
    const int o = j * 8 + (t & 7);
    const float4* gv = (const float4*)(gp + b * 512 + half * 256);
    const float4* wv = (const float4*)(w1 + (size_t)o * 512 + half * 256);
    float acc = 0.0f;
    #pragma unroll 8
    for (int i = 0; i < 64; ++i) {
        float4 g = gv[i], w = wv[i];
        acc += g.x * w.x + g.y * w.y + g.z * w.z + g.w * w.w;
    }
    __shared__ float part[256];
    part[t] = acc;
    __syncthreads();
    if (t < 128) h[b * 256 + o] = fmaxf(part[t] + part[t + 128] + b1[o], 0.0f);
}

// ---------- 3) out: inline layer2+sigmoid, then gate + bilinear2x (R2 body) ----------
__global__ __launch_bounds__(256) void out_kernel(const float* __restrict__ deeper,
                                                  const float* __restrict__ shallower,
                                                  const float* __restrict__ h,
                                                  const float* __restrict__ w2,
                                                  const float* __restrict__ b2,
                                                  float* __restrict__ out) {
    const int bc = blockIdx.x;   // 4096 = b*256 + c
    const int b = bc >> 8, c = bc & 255;
    const int t = threadIdx.x;
    __shared__ float tile[32 * 36];
    __shared__ float red[4];
    __shared__ float sv_s;
    // stage deeper tile -> LDS
    {
        float4 v = ((const float4*)(deeper + (size_t)bc * 1024))[t];
        const int row = t >> 3, col4 = t & 7;
        *(float4*)(tile + row * 36 + col4 * 4) = v;
    }
    // inline layer2: sig[b,c] = sigmoid(h[b,:].w2[c,:] + b2[c]); 1 elem/thread
    {
        float p = h[b * 256 + t] * w2[(size_t)c * 256 + t];
        #pragma unroll
        for (int off = 32; off > 0; off >>= 1) p += __shfl_down(p, off, 64);
        if ((t & 63) == 0) red[t >> 6] = p;
    }
    __syncthreads();
    if (t == 0) {
        const float dot = red[0] + red[1] + red[2] + red[3] + b2[c];
        sv_s = 1.0f / (1.0f + expf(-dot));
    }
    __syncthreads();
    const float s = sv_s;
    const float4* ssrc = (const float4*)(shallower + (size_t)bc * 4096);
    float4* dst = (float4*)(out + (size_t)bc * 4096);
    #pragma unroll
    for (int j = 0; j < 4; ++j) {
        const int f4 = t + j * 256;      // 0..1023, fully coalesced (1KB/wave/store)
        const int y = f4 >> 4;
        const int m = f4 & 15;
        const int yy = 2 * y - 1;
        const int yl = yy >> 2;
        const float wy = (float)(yy & 3) * 0.25f;
        const float wy1 = 1.0f - wy;
        const int y0 = yl < 0 ? 0 : yl;
        const int y1 = (yl + 1) > 31 ? 31 : (yl + 1);
        const float* r0 = tile + y0 * 36;
        const float* r1 = tile + y1 * 36;
        const int xa = (2 * m - 1) < 0 ? 0 : (2 * m - 1);
        const int xd = (2 * m + 2) > 31 ? 31 : (2 * m + 2);
        const float A  = r0[xa]        * wy1 + r1[xa]        * wy;
        const float Bv = r0[2 * m]     * wy1 + r1[2 * m]     * wy;
        const float Cv = r0[2 * m + 1] * wy1 + r1[2 * m + 1] * wy;
        const float D  = r0[xd]        * wy1 + r1[xd]        * wy;
        float4 sh = ssrc[f4];
        float4 o;
        o.x = fmaf(sh.x, s, 0.25f * A  + 0.75f * Bv);
        o.y = fmaf(sh.y, s, 0.75f * Bv + 0.25f * Cv);
        o.z = fmaf(sh.z, s, 0.25f * Bv + 0.75f * Cv);
        o.w = fmaf(sh.w, s, 0.75f * Cv + 0.25f * D);
        dst[f4] = o;
    }
}

extern "C" void kernel_launch(void* const* d_in, const int* in_sizes, int n_in,
                              void* d_out, int out_size, void* d_ws, size_t ws_size,
                              hipStream_t stream) {
    const float* deeper    = (const float*)d_in[0];  // [16,256,32,32]
    const float* shallower = (const float*)d_in[1];  // [16,256,64,64]
    const float* w1        = (const float*)d_in[2];  // [256,512]
    const float* b1        = (const float*)d_in[3];  // [256]
    const float* w2        = (const float*)d_in[4];  // [256,256]
    const float* b2        = (const float*)d_in[5];  // [256]
    float* outp = (float*)d_out;

    float* gp = (float*)d_ws;          // 16*512
    float* h  = gp + 16 * 512;         // 16*256

    hipLaunchKernelGGL(pool_kernel, dim3(4096), dim3(256), 0, stream, deeper, shallower, gp);
    hipLaunchKernelGGL(mlp1_kernel, dim3(32), dim3(256), 0, stream, gp, w1, b1, h);
    hipLaunchKernelGGL(out_kernel, dim3(4096), dim3(256), 0, stream,
                       deeper, shallower, h, w2, b2, outp);
}

// Round 9
// 44.310 us; speedup vs baseline: 6.9667x; 1.1727x over previous
//
#include <hip/hip_runtime.h>
#include <math.h>

// B=16, C=256, deeper 32x32, shallower 64x64 (fixed by reference).
// ws layout (floats): gp[16*512] | h[16*256]
// 3 dispatches: pool -> mlp layer1 -> out (inline layer2 + gate + upsample).
// Learned: intra-kernel cross-block sync costs 100x a dispatch boundary (R4/R5);
// few-block weight streaming costs more than a boundary (R6); inline layer2 wins (R7).

typedef float f32x4_t __attribute__((ext_vector_type(4)));  // native vec for NT store

// ---------- 1) pool: one block per (b,c); means of both inputs (proven) ----------
__global__ __launch_bounds__(256) void pool_kernel(const float* __restrict__ deeper,
                                                   const float* __restrict__ shallower,
                                                   float* __restrict__ gp) {
    const int bc = blockIdx.x;   // b*256 + c
    const int t = threadIdx.x;
    const float4* ssrc = (const float4*)(shallower + (size_t)bc * 4096);
    const float4* dsrc = (const float4*)(deeper + (size_t)bc * 1024);
    float4 a = ssrc[t], b4 = ssrc[t + 256], c4 = ssrc[t + 512], d4 = ssrc[t + 768];
    float4 e = dsrc[t];
    float s_sh = (a.x + a.y + a.z + a.w) + (b4.x + b4.y + b4.z + b4.w)
               + (c4.x + c4.y + c4.z + c4.w) + (d4.x + d4.y + d4.z + d4.w);
    float s_dp = e.x + e.y + e.z + e.w;
    #pragma unroll
    for (int off = 32; off > 0; off >>= 1) {
        s_sh += __shfl_down(s_sh, off, 64);
        s_dp += __shfl_down(s_dp, off, 64);
    }
    __shared__ float red_sh[4], red_dp[4];
    if ((t & 63) == 0) { red_sh[t >> 6] = s_sh; red_dp[t >> 6] = s_dp; }
    __syncthreads();
    if (t == 0) {
        const int bb = bc >> 8, cc = bc & 255;
        gp[bb * 512 + cc]       = (red_sh[0]+red_sh[1]+red_sh[2]+red_sh[3]) * (1.0f / 4096.0f);
        gp[bb * 512 + 256 + cc] = (red_dp[0]+red_dp[1]+red_dp[2]+red_dp[3]) * (1.0f / 1024.0f);
    }
}

// ---------- 2) mlp layer1: 256 blocks, one output column o per block ----------
// thread = (b, kchunk): 16 batches x 16 chunks of 32 floats; LDS reduce per b.
__global__ __launch_bounds__(256) void mlp1_kernel(const float* __restrict__ gp,
                                                   const float* __restrict__ w1,
                                                   const float* __restrict__ b1,
                                                   float* __restrict__ h) {
    const int o = blockIdx.x;    // 0..255
    const int t = threadIdx.x;
    const int b = t >> 4, kc = t & 15;
    const float4* gv = (const float4*)(gp + b * 512 + kc * 32);
    const float4* wv = (const float4*)(w1 + (size_t)o * 512 + kc * 32);
    float acc = 0.0f;
    #pragma unroll
    for (int i = 0; i < 8; ++i) {
        float4 g = gv[i], w = wv[i];
        acc += g.x * w.x + g.y * w.y + g.z * w.z + g.w * w.w;
    }
    __shared__ float part[256];
    part[t] = acc;
    __syncthreads();
    if (t < 16) {
        float v = 0.0f;
        #pragma unroll
        for (int k = 0; k < 16; ++k) v += part[t * 16 + k];
        h[t * 256 + o] = fmaxf(v + b1[o], 0.0f);
    }
}

// ---------- 3) out: inline layer2+sigmoid, gate + bilinear2x; NT stores ----------
__global__ __launch_bounds__(256) void out_kernel(const float* __restrict__ deeper,
                                                  const float* __restrict__ shallower,
                                                  const float* __restrict__ h,
                                                  const float* __restrict__ w2,
                                                  const float* __restrict__ b2,
                                                  float* __restrict__ out) {
    const int bc = blockIdx.x;   // 4096 = b*256 + c
    const int b = bc >> 8, c = bc & 255;
    const int t = threadIdx.x;
    __shared__ float tile[32 * 36];
    __shared__ float red[4];
    __shared__ float sv_s;

    // issue the four shallower loads FIRST: they drain under the prologue
    const float4* ssrc = (const float4*)(shallower + (size_t)bc * 4096);
    float4 sh0 = ssrc[t];
    float4 sh1 = ssrc[t + 256];
    float4 sh2 = ssrc[t + 512];
    float4 sh3 = ssrc[t + 768];

    // stage deeper tile -> LDS (stride 36: float4-aligned, bank-spread)
    {
        float4 v = ((const float4*)(deeper + (size_t)bc * 1024))[t];
        const int row = t >> 3, col4 = t & 7;
        *(float4*)(tile + row * 36 + col4 * 4) = v;
    }
    // inline layer2: sigmoid(h[b,:].w2[c,:] + b2[c]); 1 elem/thread + wave reduce
    {
        float p = h[b * 256 + t] * w2[(size_t)c * 256 + t];
        #pragma unroll
        for (int off = 32; off > 0; off >>= 1) p += __shfl_down(p, off, 64);
        if ((t & 63) == 0) red[t >> 6] = p;
    }
    __syncthreads();
    if (t == 0) {
        const float dot = red[0] + red[1] + red[2] + red[3] + b2[c];
        sv_s = 1.0f / (1.0f + expf(-dot));
    }
    __syncthreads();
    const float s = sv_s;
    f32x4_t* dst = (f32x4_t*)(out + (size_t)bc * 4096);
    float4 shv[4] = { sh0, sh1, sh2, sh3 };
    #pragma unroll
    for (int j = 0; j < 4; ++j) {
        const int f4 = t + j * 256;      // 0..1023, fully coalesced
        const int y = f4 >> 4;
        const int m = f4 & 15;
        const int yy = 2 * y - 1;
        const int yl = yy >> 2;
        const float wy = (float)(yy & 3) * 0.25f;
        const float wy1 = 1.0f - wy;
        const int y0 = yl < 0 ? 0 : yl;
        const int y1 = (yl + 1) > 31 ? 31 : (yl + 1);
        const float* r0 = tile + y0 * 36;
        const float* r1 = tile + y1 * 36;
        const int xa = (2 * m - 1) < 0 ? 0 : (2 * m - 1);
        const int xd = (2 * m + 2) > 31 ? 31 : (2 * m + 2);
        const float A  = r0[xa]        * wy1 + r1[xa]        * wy;
        const float Bv = r0[2 * m]     * wy1 + r1[2 * m]     * wy;
        const float Cv = r0[2 * m + 1] * wy1 + r1[2 * m + 1] * wy;
        const float D  = r0[xd]        * wy1 + r1[xd]        * wy;
        float4 sh = shv[j];
        f32x4_t o;
        o.x = fmaf(sh.x, s, 0.25f * A  + 0.75f * Bv);
        o.y = fmaf(sh.y, s, 0.75f * Bv + 0.25f * Cv);
        o.z = fmaf(sh.z, s, 0.25f * Bv + 0.75f * Cv);
        o.w = fmaf(sh.w, s, 0.75f * Cv + 0.25f * D);
        __builtin_nontemporal_store(o, &dst[f4]);   // write-only stream: skip cache alloc
    }
}

extern "C" void kernel_launch(void* const* d_in, const int* in_sizes, int n_in,
                              void* d_out, int out_size, void* d_ws, size_t ws_size,
                              hipStream_t stream) {
    const float* deeper    = (const float*)d_in[0];  // [16,256,32,32]
    const float* shallower = (const float*)d_in[1];  // [16,256,64,64]
    const float* w1        = (const float*)d_in[2];  // [256,512]
    const float* b1        = (const float*)d_in[3];  // [256]
    const float* w2        = (const float*)d_in[4];  // [256,256]
    const float* b2        = (const float*)d_in[5];  // [256]
    float* outp = (float*)d_out;

    float* gp = (float*)d_ws;          // 16*512
    float* h  = gp + 16 * 512;         // 16*256

    hipLaunchKernelGGL(pool_kernel, dim3(4096), dim3(256), 0, stream, deeper, shallower, gp);
    hipLaunchKernelGGL(mlp1_kernel, dim3(256), dim3(256), 0, stream, gp, w1, b1, h);
    hipLaunchKernelGGL(out_kernel, dim3(4096), dim3(256), 0, stream,
                       deeper, shallower, h, w2, b2, outp);
}